// Round 9
// baseline (161.547 us; speedup 1.0000x reference)
//
#include <hip/hip_runtime.h>
#include <cstdint>
#include <cstddef>

#define Bn 16
#define Cn 64
#define Hn 256
#define Wn 256
#define HWn (Hn * Wn)          // 65536
#define TH 8                   // tile rows
#define TW 128                 // tile cols
#define ROWS (TH + 2)          // 10
#define COLS (TW + 2)          // 130
#define NBLK (Bn * (Hn / TH) * (Wn / TW))   // 1024

typedef unsigned long long u64;
typedef u64   u64x2 __attribute__((ext_vector_type(2)));
typedef float f32x4 __attribute__((ext_vector_type(4)));

// ---- kernel C: weight sign bits + per-co params + edge-corr sums -------------
__global__ __launch_bounds__(64) void pack_weights(const float* __restrict__ w,
                                                   const float* __restrict__ b0g,
                                                   const float* __restrict__ pwg,
                                                   const float* __restrict__ b1g,
                                                   u64* __restrict__ wbits,
                                                   float4* __restrict__ par,
                                                   int* __restrict__ corrx) {
    const int co = blockIdx.x;
    const int ci = threadIdx.x;
    const float* wp = w + ((size_t)co * Cn + ci) * 9;
    float v[9];
    float asum = 0.f;
    #pragma unroll
    for (int t = 0; t < 9; ++t) { v[t] = wp[t]; asum += fabsf(v[t]); }
    u64 m[9];
    #pragma unroll
    for (int t = 0; t < 9; ++t) m[t] = __ballot(v[t] > 0.f);
    #pragma unroll
    for (int off = 32; off; off >>= 1) asum += __shfl_xor(asum, off);
    if (ci == 0) {
        int c[9];
        #pragma unroll
        for (int t = 0; t < 9; ++t) {
            wbits[co * 9 + t] = m[t];
            c[t] = 64 - 2 * (int)__popcll(m[t]);
        }
        int* cx = corrx + co * 8;
        cx[0] = c[0] + c[1] + c[2];   // top row pad
        cx[1] = c[6] + c[7] + c[8];   // bottom row pad
        cx[2] = c[0] + c[3] + c[6];   // left col pad
        cx[3] = c[2] + c[5] + c[8];   // right col pad
        cx[4] = c[0]; cx[5] = c[2];   // corner overlaps
        cx[6] = c[6]; cx[7] = c[8];
        par[co] = make_float4(asum * (1.f / (Cn * 9)), b0g[co], pwg[co], b1g[co]);
    }
}

// ---- fused kernel: pack 10x130 bit tile in LDS + reg-window conv + epilogue ---
__global__ __launch_bounds__(256) void fused(const float* __restrict__ x,
                                             const float* __restrict__ rdk,
                                             const float* __restrict__ rdb,
                                             const u64* __restrict__ wbits,
                                             const float4* __restrict__ par,
                                             const int* __restrict__ corrx,
                                             float* __restrict__ out) {
    __shared__ __align__(16) u64 s_a[ROWS][COLS];   // 10400 B
    __shared__ float2 s_rd[Cn];

    const int tid = threadIdx.x;
    // XCD-chunked bijective swizzle (1024 % 8 == 0): each XCD owns 2 images;
    // vertically adjacent tiles co-resident -> halo x rows L2-hit.
    const int bid     = blockIdx.x;
    const int logical = (bid & 7) * (NBLK / 8) + (bid >> 3);
    const int n   = logical >> 6;
    const int rem = logical & 63;
    const int h0  = (rem >> 1) * TH;
    const int w0  = (rem & 1) * TW;

    if (tid < Cn) s_rd[tid] = make_float2(rdk[tid], rdb[tid]);
    __syncthreads();

    // -------- phase 1: binarize+pack rows h0-1..h0+8, cols w0-1..w0+128 -------
    const float* xn = x + (size_t)n * Cn * HWn;
    #pragma unroll
    for (int it = 0; it < 3; ++it) {
        const int task = tid + it * 256;            // 660 tasks
        if (task < 640) {                           // interior: aligned float2
            const int r = task >> 6;                // 0..9
            const int k = task & 63;                // pair index
            const int gh = h0 - 1 + r;
            const int gw = w0 + 2 * k;
            u64 b0 = 0, b1 = 0;
            if (gh >= 0 && gh < Hn) {
                const float* xp = xn + (size_t)gh * Wn + gw;
                #pragma unroll 8
                for (int ci = 0; ci < Cn; ++ci) {
                    const float2 kb = s_rd[ci];
                    const float2 v = *reinterpret_cast<const float2*>(xp + (size_t)ci * HWn);
                    const u64 bit = 1ull << ci;
                    if (fmaf(v.x, kb.x, kb.y) > 0.f) b0 |= bit;
                    if (fmaf(v.y, kb.x, kb.y) > 0.f) b1 |= bit;
                }
            }
            s_a[r][1 + 2 * k] = b0;
            s_a[r][2 + 2 * k] = b1;
        } else if (task < 660) {                    // side halo columns
            const int t2 = task - 640;
            const int r = t2 >> 1;
            const int side = t2 & 1;
            const int gh = h0 - 1 + r;
            const int gw = side ? (w0 + TW) : (w0 - 1);
            u64 b = 0;
            if (gh >= 0 && gh < Hn && gw >= 0 && gw < Wn) {
                const float* xp = xn + (size_t)gh * Wn + gw;
                #pragma unroll 8
                for (int ci = 0; ci < Cn; ++ci) {
                    const float2 kb = s_rd[ci];
                    if (fmaf(xp[(size_t)ci * HWn], kb.x, kb.y) > 0.f) b |= 1ull << ci;
                }
            }
            s_a[r][side ? (COLS - 1) : 0] = b;
        }
    }
    __syncthreads();

    // -------- phase 2: A-window -> registers ---------------------------------
    const int r  = tid >> 5;            // 0..7
    const int c0 = (tid & 31) * 4;      // 0..124

    u64 A[3][6];                        // window rows r..r+2, s_a cols c0..c0+5
    #pragma unroll
    for (int dh = 0; dh < 3; ++dh)
        #pragma unroll
        for (int q = 0; q < 3; ++q) {
            const u64x2 t = *reinterpret_cast<const u64x2*>(&s_a[r + dh][c0 + 2 * q]);
            A[dh][2 * q]     = t.x;
            A[dh][2 * q + 1] = t.y;
        }
    __syncthreads();
    // Overwrite the head of s_a with the epilogue params (read below, so the
    // stores are live). Any later reload of s_a bytes is unsound -> the
    // compiler MUST keep A in VGPRs (blocks R4/R8's rematerialization).
    float4* parL = reinterpret_cast<float4*>(&s_a[0][0]);
    if (tid < Cn) parL[tid] = par[tid];
    __syncthreads();

    const int gw0  = w0 + c0;
    const int h    = h0 + r;
    const int htop = (h == 0), hbot = (h == Hn - 1);
    const int wl   = (gw0 == 0), wr = (gw0 + 3 == Wn - 1);
    const int need = htop | hbot | wl | wr;

    const float* xp = x   + (size_t)n * Cn * HWn + (size_t)h * Wn + gw0;
    float*       op = out + (size_t)n * Cn * HWn + (size_t)h * Wn + gw0;

    f32x4 xa = *reinterpret_cast<const f32x4*>(xp);
    #pragma unroll 2
    for (int co = 0; co < Cn; ++co) {
        const int nco = (co < Cn - 1) ? co + 1 : co;
        const f32x4 xa_n = *reinterpret_cast<const f32x4*>(xp + (size_t)nco * HWn);

        const u64* wb = wbits + co * 9;     // uniform -> SGPR s_loads
        int isum[4];
        #pragma unroll
        for (int p = 0; p < 4; ++p) {
            int acc = 0;
            #pragma unroll
            for (int dh = 0; dh < 3; ++dh) {
                acc += (int)__popcll(A[dh][p]     ^ wb[dh * 3]);
                acc += (int)__popcll(A[dh][p + 1] ^ wb[dh * 3 + 1]);
                acc += (int)__popcll(A[dh][p + 2] ^ wb[dh * 3 + 2]);
            }
            isum[p] = 576 - 2 * acc;
        }

        if (need) {
            const int* cx = corrx + co * 8;
            const int sb = (htop ? cx[0] : 0) + (hbot ? cx[1] : 0);
            #pragma unroll
            for (int p = 0; p < 4; ++p) isum[p] -= sb;
            if (wl) isum[0] -= cx[2] - (htop ? cx[4] : 0) - (hbot ? cx[6] : 0);
            if (wr) isum[3] -= cx[3] - (htop ? cx[5] : 0) - (hbot ? cx[7] : 0);
        }

        const float4 p4 = parL[co];         // LDS broadcast read (keeps stores live)
        f32x4 o;
        #pragma unroll
        for (int j = 0; j < 4; ++j) {
            float y = fmaf(p4.x, (float)isum[j], p4.y);
            y = (y >= 0.f) ? y : y * p4.z;
            o[j] = y + p4.w + xa[j];
        }
        __builtin_nontemporal_store(o, reinterpret_cast<f32x4*>(op + (size_t)co * HWn));
        xa = xa_n;
    }
}

// ---------------- host launcher ----------------
extern "C" void kernel_launch(void* const* d_in, const int* in_sizes, int n_in,
                              void* d_out, int out_size, void* d_ws, size_t ws_size,
                              hipStream_t stream) {
    const float* x      = (const float*)d_in[0];
    const float* rd_k   = (const float*)d_in[1];
    const float* rd_b   = (const float*)d_in[2];
    // d_in[3] = beta: unused in forward (STE forward = hard sign)
    const float* conv_w = (const float*)d_in[4];
    const float* pb0    = (const float*)d_in[5];
    const float* pw     = (const float*)d_in[6];
    const float* pb1    = (const float*)d_in[7];
    float* out = (float*)d_out;

    uint8_t* ws = (uint8_t*)d_ws;
    u64*    wbits = (u64*)ws;                    // 4608 B
    float4* par   = (float4*)(ws + 4608);        // 1024 B
    int*    corrx = (int*)(ws + 4608 + 1024);    // 2048 B

    pack_weights<<<Cn, 64, 0, stream>>>(conv_w, pb0, pw, pb1, wbits, par, corrx);
    fused<<<NBLK, 256, 0, stream>>>(x, rd_k, rd_b, wbits, par, corrx, out);
}